// Round 1
// baseline (187.092 us; speedup 1.0000x reference)
//
#include <hip/hip_runtime.h>

typedef __attribute__((ext_vector_type(4))) short short4v;
typedef __attribute__((ext_vector_type(8))) short short8v;
typedef __attribute__((ext_vector_type(4))) float f32x4;
typedef __attribute__((ext_vector_type(16))) float f32x16;

#define LSTRIDE 68                 // bf16 elems per LDS row (136 B; stride/8 odd -> conflict-free b64)
#define MATB (64 * LSTRIDE * 2)    // 8704 B per 64x64 bf16 matrix
#define REGA 0
#define REGB (4 * MATB)            // 34816
#define LDS_BYTES (8 * MATB)       // 69632

#define CFRAG_BYTES (7 * 8 * 2 * 4 * 1024)  // 458752: [kslot][mat][qr][t][lane][8 bf16]
#define INIT_OFF CFRAG_BYTES                // 32768: [part][qr][qc][lane][16 f32]

__device__ __forceinline__ short bf16h(float v) {
    union { float f; unsigned u; } x; x.f = v;
    unsigned r = x.u + 0x7FFFu + ((x.u >> 16) & 1u);   // RNE truncate to bf16
    return (short)(r >> 16);
}
__device__ __forceinline__ float bf16tof(short s) {
    union { unsigned u; float f; } x; x.u = ((unsigned)(unsigned short)s) << 16;
    return x.f;
}
__device__ __forceinline__ f32x16 MF(short8v a, short8v b, f32x16 c) {
    return __builtin_amdgcn_mfma_f32_32x32x16_bf16(a, b, c, 0, 0, 0);
}

// ---------------- prep: coefficients -> ws ----------------
// mat encoding: bit0 = lo, bit1 = part(0=r,1=i), bit2 = negated
__global__ void pms_prep(const float* __restrict__ coef, char* __restrict__ wsb) {
    const int blk = blockIdx.x;
    const int lane = threadIdx.x;
    const int lrow = lane & 31, lhi = lane >> 5;
    if (blk < 112) {
        const int qr  = blk & 1;
        const int km  = blk >> 1;
        const int mat = km & 7;
        const int kk  = km >> 3;            // kslot 0..6 <-> coefficient index kk+1
        const int part = (mat >> 1) & 1;
        const int lo   = mat & 1;
        const int neg  = mat >> 2;
        const float* C = coef + (size_t)((kk + 1) * 2 + part) * 4096;
        for (int t = 0; t < 4; ++t) {
            short8v o;
            #pragma unroll
            for (int j = 0; j < 8; ++j) {
                int krow = 16 * t + 8 * lhi + j;
                int col  = 32 * qr + lrow;
                float v = C[krow * 64 + col];           // C^T[row=col][k=krow] = C[krow][col]
                if (neg) v = -v;
                short hh = bf16h(v);
                o[j] = lo ? bf16h(v - bf16tof(hh)) : hh;
            }
            *(short8v*)(wsb + ((size_t)blk * 4 + t) * 1024 + lane * 16) = o;
        }
    } else {
        const int id = blk - 112;           // [part][qr][qc]
        const int qc = id & 1, qr = (id >> 1) & 1, part = id >> 2;
        const float* C0 = coef + (size_t)part * 4096;
        float* dst = (float*)(wsb + INIT_OFF + (size_t)(((part * 2 + qr) * 2 + qc) * 64 + lane) * 64);
        #pragma unroll
        for (int v = 0; v < 16; ++v) {
            int r = 32 * qr + (v & 3) + 8 * (v >> 2) + 4 * lhi;  // D-layout row
            int c = 32 * qc + lrow;                               // D-layout col
            dst[v] = C0[c * 64 + r];        // C0^T[r][c] = C0[c][r]
        }
    }
}

// ---------------- main ----------------
__global__ __launch_bounds__(256, 2) void pms_main(
    const float* __restrict__ x, const char* __restrict__ wsb,
    float* __restrict__ out)
{
    extern __shared__ char smem[];
    const int tid  = threadIdx.x;
    const int lane = tid & 63;
    const int w    = tid >> 6;
    const int qr = w >> 1, qc = w & 1;
    const int lrow = lane & 31, lhi = lane >> 5;
    const size_t b = blockIdx.x;
    const float* xb = x + b * 8192;

    // ---- stage X into region A as split bf16 (doubles as T_1) ----
    #pragma unroll
    for (int s = 0; s < 8; ++s) {
        int f = s * 1024 + tid * 4;
        int p = f >> 12, m = (f >> 6) & 63, c = f & 63;
        f32x4 v = *(const f32x4*)(xb + f);
        short4v h, l;
        #pragma unroll
        for (int j = 0; j < 4; ++j) {
            short hh = bf16h(v[j]);
            h[j] = hh;
            l[j] = bf16h(v[j] - bf16tof(hh));
        }
        int off = (m * LSTRIDE + c) * 2;
        *(short4v*)(smem + REGA + (p * 2 + 0) * MATB + off) = h;
        *(short4v*)(smem + REGA + (p * 2 + 1) * MATB + off) = l;
    }
    __syncthreads();

    // ---- one-time A-fragments of X^T (held in registers all 6 iterations) ----
    short8v xa[2][2][4];   // [r/i][h/l][ktile]
    #pragma unroll
    for (int pi = 0; pi < 2; ++pi)
    #pragma unroll
    for (int hl = 0; hl < 2; ++hl)
    #pragma unroll
    for (int t = 0; t < 4; ++t) {
        const short* mp = (const short*)(smem + REGA + (pi * 2 + hl) * MATB);
        short8v a;
        #pragma unroll
        for (int j = 0; j < 8; ++j)
            a[j] = mp[(16 * t + 8 * lhi + j) * LSTRIDE + 32 * qr + lrow];  // X^T[r][k]=X[k][r]
        xa[pi][hl][t] = a;
    }

    // ---- accumulators init = C0^T fragments ----
    f32x16 accRr, accRi;
    {
        const f32x4* p0 = (const f32x4*)(wsb + INIT_OFF + (size_t)(((0 + qr) * 2 + qc) * 64 + lane) * 64);
        const f32x4* p1 = (const f32x4*)(wsb + INIT_OFF + (size_t)(((2 + qr) * 2 + qc) * 64 + lane) * 64);
        #pragma unroll
        for (int g = 0; g < 4; ++g) {
            f32x4 a = p0[g], c4 = p1[g];
            #pragma unroll
            for (int j = 0; j < 4; ++j) { accRr[4 * g + j] = a[j]; accRi[4 * g + j] = c4[j]; }
        }
    }

    // B-fragment: lane reads lds_T[m = 32qc+lrow][k = 16t+8lhi .. +7], two b64s
    auto ldB = [&](int rbase, int mat, int t) -> short8v {
        const short4v* p = (const short4v*)(smem + rbase + mat * MATB
                             + (32 * qc + lrow) * (LSTRIDE * 2) + 32 * t + 16 * lhi);
        short4v a = p[0], c4 = p[1];
        short8v r;
        #pragma unroll
        for (int j = 0; j < 4; ++j) { r[j] = a[j]; r[j + 4] = c4[j]; }
        return r;
    };

    // coefficient step: Rr^T += Cr^T Tr^T + (-Ci^T) Ti^T ; Ri^T += Ci^T Tr^T + (k1? +Cr^T : -Cr^T) Ti^T
    auto coeff = [&](int kslot, int rbase, bool k1) {
        #pragma unroll
        for (int st = 0; st < 2; ++st) {
            short8v ca[4][4];
            #pragma unroll
            for (int mi = 0; mi < 4; ++mi) {
                int mat = (st == 0) ? (mi == 0 ? 0 : mi == 1 ? 1 : mi == 2 ? 6 : 7)
                                    : (mi == 0 ? 2 : mi == 1 ? 3 : mi == 2 ? (k1 ? 0 : 4) : (k1 ? 1 : 5));
                #pragma unroll
                for (int t = 0; t < 4; ++t)
                    ca[mi][t] = *(const short8v*)(wsb
                        + (((size_t)(kslot * 8 + mat) * 2 + qr) * 4 + t) * 1024 + lane * 16);
            }
            f32x16 acc = (st == 0) ? accRr : accRi;
            #pragma unroll
            for (int t = 0; t < 4; ++t) {
                short8v Brh = ldB(rbase, 0, t), Brl = ldB(rbase, 1, t);
                short8v Bih = ldB(rbase, 2, t), Bil = ldB(rbase, 3, t);
                acc = MF(ca[0][t], Brh, acc);
                acc = MF(ca[0][t], Brl, acc);
                acc = MF(ca[1][t], Brh, acc);
                acc = MF(ca[2][t], Bih, acc);
                acc = MF(ca[2][t], Bil, acc);
                acc = MF(ca[3][t], Bih, acc);
            }
            if (st == 0) accRr = acc; else accRi = acc;
        }
    };

    int cur = REGA, nxt = REGB;
    coeff(0, REGA, true);          // k=1 term, T_1 = X

    for (int k = 2; k <= 7; ++k) {
        // chain: Trn^T = Xr^T Tr^T - Xi^T Ti^T ; Tin^T = Xi^T Tr^T + Xr^T Ti^T
        f32x16 aTr, aTi;
        #pragma unroll
        for (int v = 0; v < 16; ++v) { aTr[v] = 0.f; aTi[v] = 0.f; }
        #pragma unroll
        for (int t = 0; t < 4; ++t) {
            short8v Brh = ldB(cur, 0, t), Brl = ldB(cur, 1, t);
            short8v Bih = ldB(cur, 2, t), Bil = ldB(cur, 3, t);
            short8v nBih, nBil;
            #pragma unroll
            for (int j = 0; j < 8; ++j) {
                nBih[j] = Bih[j] ^ (short)0x8000;
                nBil[j] = Bil[j] ^ (short)0x8000;
            }
            aTr = MF(xa[0][0][t], Brh, aTr);
            aTr = MF(xa[0][0][t], Brl, aTr);
            aTr = MF(xa[0][1][t], Brh, aTr);
            aTr = MF(xa[1][0][t], nBih, aTr);
            aTr = MF(xa[1][0][t], nBil, aTr);
            aTr = MF(xa[1][1][t], nBih, aTr);
            aTi = MF(xa[1][0][t], Brh, aTi);
            aTi = MF(xa[1][0][t], Brl, aTi);
            aTi = MF(xa[1][1][t], Brh, aTi);
            aTi = MF(xa[0][0][t], Bih, aTi);
            aTi = MF(xa[0][0][t], Bil, aTi);
            aTi = MF(xa[0][1][t], Bih, aTi);
        }
        // split to bf16 h/l and write T_new (row-major [m=col][k=row], 4x b64 per matrix)
        {
            const int c = 32 * qc + lrow;
            #pragma unroll
            for (int g = 0; g < 4; ++g) {
                int rbse = 32 * qr + 8 * g + 4 * lhi;
                short4v hr, lr4, hi4, li4;
                #pragma unroll
                for (int j = 0; j < 4; ++j) {
                    float vr = aTr[4 * g + j];
                    short hh = bf16h(vr);
                    hr[j] = hh; lr4[j] = bf16h(vr - bf16tof(hh));
                    float vi = aTi[4 * g + j];
                    short h2 = bf16h(vi);
                    hi4[j] = h2; li4[j] = bf16h(vi - bf16tof(h2));
                }
                int off = (c * LSTRIDE + rbse) * 2;
                *(short4v*)(smem + nxt + 0 * MATB + off) = hr;
                *(short4v*)(smem + nxt + 1 * MATB + off) = lr4;
                *(short4v*)(smem + nxt + 2 * MATB + off) = hi4;
                *(short4v*)(smem + nxt + 3 * MATB + off) = li4;
            }
        }
        __syncthreads();
        coeff(k - 1, nxt, false);
        int tmp = cur; cur = nxt; nxt = tmp;
    }

    // ---- transpose result through LDS (region B is dead), coalesced store ----
    {
        const int c = 32 * qc + lrow;
        #pragma unroll
        for (int g = 0; g < 4; ++g) {
            int rbse = 32 * qr + 8 * g + 4 * lhi;
            f32x4 vr, vi;
            #pragma unroll
            for (int j = 0; j < 4; ++j) { vr[j] = accRr[4 * g + j]; vi[j] = accRi[4 * g + j]; }
            *(f32x4*)(smem + REGB + (size_t)(0 * 4352 + c * LSTRIDE + rbse) * 4) = vr;
            *(f32x4*)(smem + REGB + (size_t)(1 * 4352 + c * LSTRIDE + rbse) * 4) = vi;
        }
    }
    __syncthreads();
    float* ob = out + b * 8192;
    #pragma unroll
    for (int s = 0; s < 8; ++s) {
        int f = s * 1024 + tid * 4;
        int p = f >> 12, m = (f >> 6) & 63, n = f & 63;
        *(f32x4*)(ob + f) = *(const f32x4*)(smem + REGB + (size_t)(p * 4352 + m * LSTRIDE + n) * 4);
    }
}

extern "C" void kernel_launch(void* const* d_in, const int* in_sizes, int n_in,
                              void* d_out, int out_size, void* d_ws, size_t ws_size,
                              hipStream_t stream) {
    const float* x    = (const float*)d_in[0];
    const float* coef = (const float*)d_in[1];
    float* out = (float*)d_out;
    char*  wsb = (char*)d_ws;
    const int B = in_sizes[0] / 8192;   // 2048

    // allow >64KB dynamic LDS (gfx950 supports 160KB/WG); ignore error if unsupported
    (void)hipFuncSetAttribute(reinterpret_cast<const void*>(&pms_main),
                              hipFuncAttributeMaxDynamicSharedMemorySize, LDS_BYTES);

    pms_prep<<<120, 64, 0, stream>>>(coef, wsb);
    pms_main<<<B, 256, LDS_BYTES, stream>>>(x, wsb, out);
}

// Round 2
// 164.147 us; speedup vs baseline: 1.1398x; 1.1398x over previous
//
#include <hip/hip_runtime.h>

typedef __attribute__((ext_vector_type(4))) short short4v;
typedef __attribute__((ext_vector_type(8))) short short8v;
typedef __attribute__((ext_vector_type(4))) unsigned int uint4v;
typedef __attribute__((ext_vector_type(4))) float f32x4;
typedef __attribute__((ext_vector_type(16))) float f32x16;

#define LSTRIDE 68                 // bf16 elems per LDS row (136 B; stride/8 odd -> conflict-free b64)
#define MATB (64 * LSTRIDE * 2)    // 8704 B per 64x64 bf16 matrix
#define REGA 0
#define REGB (4 * MATB)            // 34816
#define LDS_BYTES (8 * MATB)       // 69632

// ws: [kslot 0..6][mat 0..3][qr][t][lane*16B]; mat: 0=Cr_h 1=Cr_l 2=Ci_h 3=Ci_l
#define CFRAG_BYTES (7 * 4 * 2 * 4 * 1024)  // 229376
#define INIT_OFF CFRAG_BYTES                // + 32768: [part][qr][qc][lane][16 f32]

__device__ __forceinline__ short bf16h(float v) {
    union { float f; unsigned u; } x; x.f = v;
    unsigned r = x.u + 0x7FFFu + ((x.u >> 16) & 1u);   // RNE truncate to bf16
    return (short)(r >> 16);
}
__device__ __forceinline__ float bf16tof(short s) {
    union { unsigned u; float f; } x; x.u = ((unsigned)(unsigned short)s) << 16;
    return x.f;
}
__device__ __forceinline__ f32x16 MF(short8v a, short8v b, f32x16 c) {
    return __builtin_amdgcn_mfma_f32_32x32x16_bf16(a, b, c, 0, 0, 0);
}
__device__ __forceinline__ short8v negf(short8v a) {   // negate 8 bf16 (packed xor)
    uint4v u = __builtin_bit_cast(uint4v, a);
    u ^= 0x80008000u;
    return __builtin_bit_cast(short8v, u);
}

// ---------------- prep: coefficients -> ws ----------------
__global__ void pms_prep(const float* __restrict__ coef, char* __restrict__ wsb) {
    const int blk = blockIdx.x;
    const int lane = threadIdx.x;
    const int lrow = lane & 31, lhi = lane >> 5;
    if (blk < 56) {
        const int qr  = blk & 1;
        const int km  = blk >> 1;
        const int mat = km & 3;
        const int kk  = km >> 2;            // kslot 0..6 <-> coefficient index kk+1
        const int part = mat >> 1;
        const int lo   = mat & 1;
        const float* C = coef + (size_t)((kk + 1) * 2 + part) * 4096;
        for (int t = 0; t < 4; ++t) {
            short8v o;
            #pragma unroll
            for (int j = 0; j < 8; ++j) {
                int krow = 16 * t + 8 * lhi + j;
                int col  = 32 * qr + lrow;
                float v = C[krow * 64 + col];           // C^T[col][krow]
                short hh = bf16h(v);
                o[j] = lo ? bf16h(v - bf16tof(hh)) : hh;
            }
            *(short8v*)(wsb + ((size_t)blk * 4 + t) * 1024 + lane * 16) = o;
        }
    } else {
        const int id = blk - 56;            // [part][qr][qc]
        const int qc = id & 1, qr = (id >> 1) & 1, part = id >> 2;
        const float* C0 = coef + (size_t)part * 4096;
        float* dst = (float*)(wsb + INIT_OFF + (size_t)(((part * 2 + qr) * 2 + qc) * 64 + lane) * 64);
        #pragma unroll
        for (int v = 0; v < 16; ++v) {
            int r = 32 * qr + (v & 3) + 8 * (v >> 2) + 4 * lhi;  // D-layout row
            int c = 32 * qc + lrow;                               // D-layout col
            dst[v] = C0[c * 64 + r];        // C0^T[r][c]
        }
    }
}

// ---------------- main ----------------
__global__ __launch_bounds__(256, 2) void pms_main(
    const float* __restrict__ x, const char* __restrict__ wsb,
    float* __restrict__ out)
{
    extern __shared__ char smem[];
    const int tid  = threadIdx.x;
    const int lane = tid & 63;
    const int w    = tid >> 6;
    const int qr = w >> 1, qc = w & 1;
    const int lrow = lane & 31, lhi = lane >> 5;
    const size_t b = blockIdx.x;
    const float* xb = x + b * 8192;

    // ---- stage X into region A as split bf16 (doubles as T_1) ----
    #pragma unroll
    for (int s = 0; s < 8; ++s) {
        int f = s * 1024 + tid * 4;
        int p = f >> 12, m = (f >> 6) & 63, c = f & 63;
        f32x4 v = *(const f32x4*)(xb + f);
        short4v h, l;
        #pragma unroll
        for (int j = 0; j < 4; ++j) {
            short hh = bf16h(v[j]);
            h[j] = hh;
            l[j] = bf16h(v[j] - bf16tof(hh));
        }
        int off = (m * LSTRIDE + c) * 2;
        *(short4v*)(smem + REGA + (p * 2 + 0) * MATB + off) = h;
        *(short4v*)(smem + REGA + (p * 2 + 1) * MATB + off) = l;
    }
    __syncthreads();

    // ---- one-time A-fragments of X^T (held in registers all iterations) ----
    short8v xa[2][2][4];   // [r/i][h/l][ktile]
    #pragma unroll
    for (int pi = 0; pi < 2; ++pi)
    #pragma unroll
    for (int hl = 0; hl < 2; ++hl)
    #pragma unroll
    for (int t = 0; t < 4; ++t) {
        const short* mp = (const short*)(smem + REGA + (pi * 2 + hl) * MATB);
        short8v a;
        #pragma unroll
        for (int j = 0; j < 8; ++j)
            a[j] = mp[(16 * t + 8 * lhi + j) * LSTRIDE + 32 * qr + lrow];  // X^T[r][k]
        xa[pi][hl][t] = a;
    }

    // ---- accumulators init = C0^T fragments ----
    f32x16 accRr, accRi;
    {
        const f32x4* p0 = (const f32x4*)(wsb + INIT_OFF + (size_t)(((0 + qr) * 2 + qc) * 64 + lane) * 64);
        const f32x4* p1 = (const f32x4*)(wsb + INIT_OFF + (size_t)(((2 + qr) * 2 + qc) * 64 + lane) * 64);
        #pragma unroll
        for (int g = 0; g < 4; ++g) {
            f32x4 a = p0[g], c4 = p1[g];
            #pragma unroll
            for (int j = 0; j < 4; ++j) { accRr[4 * g + j] = a[j]; accRi[4 * g + j] = c4[j]; }
        }
    }

    // B-fragment: lane reads lds_T[m = 32qc+lrow][k = 16t+8lhi .. +7], two b64s
    auto ldB = [&](int rbase, int mat, int t) -> short8v {
        const short4v* p = (const short4v*)(smem + rbase + mat * MATB
                             + (32 * qc + lrow) * (LSTRIDE * 2) + 32 * t + 16 * lhi);
        short4v a = p[0], c4 = p[1];
        short8v r;
        #pragma unroll
        for (int j = 0; j < 4; ++j) { r[j] = a[j]; r[j + 4] = c4[j]; }
        return r;
    };

    int cur = REGA, nxt = REGB;

    // ---- fused loop: iteration k applies coeff C_{k-1} to T_{k-1} AND computes T_k ----
    for (int k = 2; k <= 7; ++k) {
        const char* cw = wsb + (size_t)(k - 2) * 32768;   // kslot k-2
        const bool k1 = (k == 2);
        f32x16 aTr, aTi;
        #pragma unroll
        for (int v = 0; v < 16; ++v) { aTr[v] = 0.f; aTi[v] = 0.f; }

        #pragma unroll
        for (int t = 0; t < 4; ++t) {
            // coefficient A-frags (L2-resident, 16B/lane each)
            short8v cRh = *(const short8v*)(cw + ((0 * 2 + qr) * 4 + t) * 1024 + lane * 16);
            short8v cRl = *(const short8v*)(cw + ((1 * 2 + qr) * 4 + t) * 1024 + lane * 16);
            short8v cIh = *(const short8v*)(cw + ((2 * 2 + qr) * 4 + t) * 1024 + lane * 16);
            short8v cIl = *(const short8v*)(cw + ((3 * 2 + qr) * 4 + t) * 1024 + lane * 16);
            // B-frags of T_{k-1}
            short8v Brh = ldB(cur, 0, t), Brl = ldB(cur, 1, t);
            short8v Bih = ldB(cur, 2, t), Bil = ldB(cur, 3, t);
            short8v nBih = negf(Bih), nBil = negf(Bil);        // -Ti
            short8v sBih = k1 ? Bih : nBih;                    // sign quirk: +Cr*Ti at k=1 only
            short8v sBil = k1 ? Bil : nBil;

            // 24 MFMAs, 4 independent chains round-robin
            accRr = MF(cRh, Brh, accRr);
            accRi = MF(cIh, Brh, accRi);
            aTr   = MF(xa[0][0][t], Brh, aTr);
            aTi   = MF(xa[1][0][t], Brh, aTi);

            accRr = MF(cRh, Brl, accRr);
            accRi = MF(cIh, Brl, accRi);
            aTr   = MF(xa[0][0][t], Brl, aTr);
            aTi   = MF(xa[1][0][t], Brl, aTi);

            accRr = MF(cRl, Brh, accRr);
            accRi = MF(cIl, Brh, accRi);
            aTr   = MF(xa[0][1][t], Brh, aTr);
            aTi   = MF(xa[1][1][t], Brh, aTi);

            accRr = MF(cIh, nBih, accRr);      // -Ci*Ti
            accRi = MF(cRh, sBih, accRi);      // ±Cr*Ti
            aTr   = MF(xa[1][0][t], nBih, aTr);// -Xi*Ti
            aTi   = MF(xa[0][0][t], Bih, aTi); // +Xr*Ti

            accRr = MF(cIh, nBil, accRr);
            accRi = MF(cRh, sBil, accRi);
            aTr   = MF(xa[1][0][t], nBil, aTr);
            aTi   = MF(xa[0][0][t], Bil, aTi);

            accRr = MF(cIl, nBih, accRr);
            accRi = MF(cRl, sBih, accRi);
            aTr   = MF(xa[1][1][t], nBih, aTr);
            aTi   = MF(xa[0][1][t], Bih, aTi);
        }

        // split aTr/aTi to bf16 h/l and write T_k (row-major [m=col][k=row])
        {
            const int c = 32 * qc + lrow;
            #pragma unroll
            for (int g = 0; g < 4; ++g) {
                int rbse = 32 * qr + 8 * g + 4 * lhi;
                short4v hr, lr4, hi4, li4;
                #pragma unroll
                for (int j = 0; j < 4; ++j) {
                    float vr = aTr[4 * g + j];
                    short hh = bf16h(vr);
                    hr[j] = hh; lr4[j] = bf16h(vr - bf16tof(hh));
                    float vi = aTi[4 * g + j];
                    short h2 = bf16h(vi);
                    hi4[j] = h2; li4[j] = bf16h(vi - bf16tof(h2));
                }
                int off = (c * LSTRIDE + rbse) * 2;
                *(short4v*)(smem + nxt + 0 * MATB + off) = hr;
                *(short4v*)(smem + nxt + 1 * MATB + off) = lr4;
                *(short4v*)(smem + nxt + 2 * MATB + off) = hi4;
                *(short4v*)(smem + nxt + 3 * MATB + off) = li4;
            }
        }
        __syncthreads();
        int tmp = cur; cur = nxt; nxt = tmp;
    }

    // ---- final coefficient term: C_7 (kslot 6) on T_7, no chain ----
    {
        const char* cw = wsb + (size_t)6 * 32768;
        #pragma unroll
        for (int t = 0; t < 4; ++t) {
            short8v cRh = *(const short8v*)(cw + ((0 * 2 + qr) * 4 + t) * 1024 + lane * 16);
            short8v cRl = *(const short8v*)(cw + ((1 * 2 + qr) * 4 + t) * 1024 + lane * 16);
            short8v cIh = *(const short8v*)(cw + ((2 * 2 + qr) * 4 + t) * 1024 + lane * 16);
            short8v cIl = *(const short8v*)(cw + ((3 * 2 + qr) * 4 + t) * 1024 + lane * 16);
            short8v Brh = ldB(cur, 0, t), Brl = ldB(cur, 1, t);
            short8v Bih = ldB(cur, 2, t), Bil = ldB(cur, 3, t);
            short8v nBih = negf(Bih), nBil = negf(Bil);

            accRr = MF(cRh, Brh, accRr);
            accRi = MF(cIh, Brh, accRi);
            accRr = MF(cRh, Brl, accRr);
            accRi = MF(cIh, Brl, accRi);
            accRr = MF(cRl, Brh, accRr);
            accRi = MF(cIl, Brh, accRi);
            accRr = MF(cIh, nBih, accRr);
            accRi = MF(cRh, nBih, accRi);
            accRr = MF(cIh, nBil, accRr);
            accRi = MF(cRh, nBil, accRi);
            accRr = MF(cIl, nBih, accRr);
            accRi = MF(cRl, nBih, accRi);
        }
    }

    // ---- transpose result through LDS (nxt region is dead), coalesced store ----
    {
        const int c = 32 * qc + lrow;
        #pragma unroll
        for (int g = 0; g < 4; ++g) {
            int rbse = 32 * qr + 8 * g + 4 * lhi;
            f32x4 vr, vi;
            #pragma unroll
            for (int j = 0; j < 4; ++j) { vr[j] = accRr[4 * g + j]; vi[j] = accRi[4 * g + j]; }
            *(f32x4*)(smem + nxt + (size_t)(0 * 4352 + c * LSTRIDE + rbse) * 4) = vr;
            *(f32x4*)(smem + nxt + (size_t)(1 * 4352 + c * LSTRIDE + rbse) * 4) = vi;
        }
    }
    __syncthreads();
    float* ob = out + b * 8192;
    #pragma unroll
    for (int s = 0; s < 8; ++s) {
        int f = s * 1024 + tid * 4;
        int p = f >> 12, m = (f >> 6) & 63, n = f & 63;
        *(f32x4*)(ob + f) = *(const f32x4*)(smem + nxt + (size_t)(p * 4352 + m * LSTRIDE + n) * 4);
    }
}

extern "C" void kernel_launch(void* const* d_in, const int* in_sizes, int n_in,
                              void* d_out, int out_size, void* d_ws, size_t ws_size,
                              hipStream_t stream) {
    const float* x    = (const float*)d_in[0];
    const float* coef = (const float*)d_in[1];
    float* out = (float*)d_out;
    char*  wsb = (char*)d_ws;
    const int B = in_sizes[0] / 8192;   // 2048

    (void)hipFuncSetAttribute(reinterpret_cast<const void*>(&pms_main),
                              hipFuncAttributeMaxDynamicSharedMemorySize, LDS_BYTES);

    pms_prep<<<64, 64, 0, stream>>>(coef, wsb);
    pms_main<<<B, 256, LDS_BYTES, stream>>>(x, wsb, out);
}

// Round 4
// 157.791 us; speedup vs baseline: 1.1857x; 1.0403x over previous
//
#include <hip/hip_runtime.h>

typedef __attribute__((ext_vector_type(4))) short short4v;
typedef __attribute__((ext_vector_type(8))) short short8v;
typedef __attribute__((ext_vector_type(2))) unsigned int uint2v;
typedef __attribute__((ext_vector_type(4))) unsigned int uint4v;
typedef __attribute__((ext_vector_type(4))) float f32x4;
typedef __attribute__((ext_vector_type(16))) float f32x16;

#define LSTRIDE 68                 // bf16 elems per LDS row (136 B; stride/8 odd -> conflict-free b64)
#define MATB (64 * LSTRIDE * 2)    // 8704 B per 64x64 bf16 matrix
#define LDS_BYTES (4 * MATB)       // 34816: single in-place T region (mats: Trh, Trl, Tih, Til)

// ws: [kslot 0..6][mat 0..3][qr][t][lane*16B]; mat: 0=Cr_h 1=Cr_l 2=Ci_h 3=Ci_l
#define CFRAG_BYTES (7 * 4 * 2 * 4 * 1024)  // 229376
#define INIT_OFF CFRAG_BYTES                // + 32768: [part][qr][qc][lane][16 f32]

__device__ __forceinline__ short bf16h(float v) {
    union { float f; unsigned u; } x; x.f = v;
    unsigned r = x.u + 0x7FFFu + ((x.u >> 16) & 1u);
    return (short)(r >> 16);
}
__device__ __forceinline__ float bf16tof(short s) {
    union { unsigned u; float f; } x; x.u = ((unsigned)(unsigned short)s) << 16;
    return x.f;
}
// split two f32 into packed-bf16 high parts and packed-bf16 low (residual) parts
struct HL { unsigned h, l; };
__device__ __forceinline__ HL split2(float v0, float v1) {
    unsigned hp, lp;
    asm("v_cvt_pk_bf16_f32 %0, %1, %2" : "=v"(hp) : "v"(v0), "v"(v1));
    union { unsigned u; float f; } a, b;
    a.u = hp << 16;            // float of bf16(v0)
    b.u = hp & 0xffff0000u;    // float of bf16(v1)
    float l0 = v0 - a.f, l1 = v1 - b.f;
    asm("v_cvt_pk_bf16_f32 %0, %1, %2" : "=v"(lp) : "v"(l0), "v"(l1));
    HL r; r.h = hp; r.l = lp; return r;
}
__device__ __forceinline__ f32x16 MF(short8v a, short8v b, f32x16 c) {
    return __builtin_amdgcn_mfma_f32_32x32x16_bf16(a, b, c, 0, 0, 0);
}
__device__ __forceinline__ short8v negf(short8v a) {   // negate 8 bf16 (packed xor)
    uint4v u = __builtin_bit_cast(uint4v, a);
    u ^= 0x80008000u;
    return __builtin_bit_cast(short8v, u);
}

// ---------------- prep: coefficients -> ws ----------------
__global__ void pms_prep(const float* __restrict__ coef, char* __restrict__ wsb) {
    const int blk = blockIdx.x;
    const int lane = threadIdx.x;
    const int lrow = lane & 31, lhi = lane >> 5;
    if (blk < 56) {
        const int qr  = blk & 1;
        const int km  = blk >> 1;
        const int mat = km & 3;
        const int kk  = km >> 2;            // kslot 0..6 <-> coefficient index kk+1
        const int part = mat >> 1;
        const int lo   = mat & 1;
        const float* C = coef + (size_t)((kk + 1) * 2 + part) * 4096;
        for (int t = 0; t < 4; ++t) {
            short8v o;
            #pragma unroll
            for (int j = 0; j < 8; ++j) {
                int krow = 16 * t + 8 * lhi + j;
                int col  = 32 * qr + lrow;
                float v = C[krow * 64 + col];           // C^T[col][krow]
                short hh = bf16h(v);
                o[j] = lo ? bf16h(v - bf16tof(hh)) : hh;
            }
            *(short8v*)(wsb + ((size_t)blk * 4 + t) * 1024 + lane * 16) = o;
        }
    } else {
        const int id = blk - 56;            // [part][qr][qc]
        const int qc = id & 1, qr = (id >> 1) & 1, part = id >> 2;
        const float* C0 = coef + (size_t)part * 4096;
        float* dst = (float*)(wsb + INIT_OFF + (size_t)(((part * 2 + qr) * 2 + qc) * 64 + lane) * 64);
        #pragma unroll
        for (int v = 0; v < 16; ++v) {
            int r = 32 * qr + (v & 3) + 8 * (v >> 2) + 4 * lhi;  // D-layout row
            int c = 32 * qc + lrow;                               // D-layout col
            dst[v] = C0[c * 64 + r];        // C0^T[r][c]
        }
    }
}

// ---------------- main ----------------
__global__ __launch_bounds__(256, 3) void pms_main(
    const float* __restrict__ x, const char* __restrict__ wsb,
    float* __restrict__ out)
{
    extern __shared__ char smem[];
    const int tid  = threadIdx.x;
    const int lane = tid & 63;
    const int w    = tid >> 6;
    const int qr = w >> 1, qc = w & 1;
    const int lrow = lane & 31, lhi = lane >> 5;
    const size_t b = blockIdx.x;
    const float* xb = x + b * 8192;

    // ---- stage X (row-major) as split bf16; doubles as T_1 ----
    #pragma unroll
    for (int s = 0; s < 8; ++s) {
        int f = s * 1024 + tid * 4;
        int p = f >> 12, m = (f >> 6) & 63, c = f & 63;
        f32x4 v = *(const f32x4*)(xb + f);
        HL a01 = split2(v[0], v[1]);
        HL a23 = split2(v[2], v[3]);
        uint2v h, l;
        h[0] = a01.h; l[0] = a01.l;
        h[1] = a23.h; l[1] = a23.l;
        int off = (m * LSTRIDE + c) * 2;
        *(uint2v*)(smem + (p * 2 + 0) * MATB + off) = h;
        *(uint2v*)(smem + (p * 2 + 1) * MATB + off) = l;
    }
    __syncthreads();

    // ---- one-time A-fragments of X^T (registers, all iterations) ----
    short8v xa[2][2][4];   // [r/i][h/l][ktile]
    #pragma unroll
    for (int pi = 0; pi < 2; ++pi)
    #pragma unroll
    for (int hl = 0; hl < 2; ++hl)
    #pragma unroll
    for (int t = 0; t < 4; ++t) {
        const short* mp = (const short*)(smem + (pi * 2 + hl) * MATB);
        short8v a;
        #pragma unroll
        for (int j = 0; j < 8; ++j)
            a[j] = mp[(16 * t + 8 * lhi + j) * LSTRIDE + 32 * qr + lrow];  // X^T[r][k]
        xa[pi][hl][t] = a;
    }

    // ---- accumulators init = C0^T fragments ----
    f32x16 accRr, accRi;
    {
        const f32x4* p0 = (const f32x4*)(wsb + INIT_OFF + (size_t)(((0 + qr) * 2 + qc) * 64 + lane) * 64);
        const f32x4* p1 = (const f32x4*)(wsb + INIT_OFF + (size_t)(((2 + qr) * 2 + qc) * 64 + lane) * 64);
        #pragma unroll
        for (int g = 0; g < 4; ++g) {
            f32x4 a = p0[g], c4 = p1[g];
            #pragma unroll
            for (int j = 0; j < 4; ++j) { accRr[4 * g + j] = a[j]; accRi[4 * g + j] = c4[j]; }
        }
    }

    // B-fragment: lane reads lds_T[n = 32qc+lrow][k = 16t+8lhi .. +7], two b64s
    auto ldB = [&](int mat, int t) -> short8v {
        const short4v* p = (const short4v*)(smem + mat * MATB
                             + (32 * qc + lrow) * (LSTRIDE * 2) + 32 * t + 16 * lhi);
        short4v a = p[0], c4 = p[1];
        short8v r;
        #pragma unroll
        for (int j = 0; j < 4; ++j) { r[j] = a[j]; r[j + 4] = c4[j]; }
        return r;
    };

    // ---- fused loop: iteration k applies C_{k-1} to T_{k-1} AND computes T_k (in place) ----
    for (int k = 2; k <= 7; ++k) {
        const char* cw = wsb + (size_t)(k - 2) * 32768;   // kslot k-2
        const bool k1 = (k == 2);
        f32x16 aTr, aTi;
        #pragma unroll
        for (int v = 0; v < 16; ++v) { aTr[v] = 0.f; aTi[v] = 0.f; }

        #pragma unroll
        for (int t = 0; t < 4; ++t) {
            short8v cRh = *(const short8v*)(cw + ((0 * 2 + qr) * 4 + t) * 1024 + lane * 16);
            short8v cRl = *(const short8v*)(cw + ((1 * 2 + qr) * 4 + t) * 1024 + lane * 16);
            short8v cIh = *(const short8v*)(cw + ((2 * 2 + qr) * 4 + t) * 1024 + lane * 16);
            short8v cIl = *(const short8v*)(cw + ((3 * 2 + qr) * 4 + t) * 1024 + lane * 16);
            short8v Brh = ldB(0, t), Brl = ldB(1, t);
            short8v Bih = ldB(2, t), Bil = ldB(3, t);
            short8v nBih = negf(Bih), nBil = negf(Bil);        // -Ti
            short8v sBih = k1 ? Bih : nBih;                    // sign quirk: +Cr*Ti at k=1 only
            short8v sBil = k1 ? Bil : nBil;

            // 24 MFMAs, 4 independent chains round-robin
            accRr = MF(cRh, Brh, accRr);
            accRi = MF(cIh, Brh, accRi);
            aTr   = MF(xa[0][0][t], Brh, aTr);
            aTi   = MF(xa[1][0][t], Brh, aTi);

            accRr = MF(cRh, Brl, accRr);
            accRi = MF(cIh, Brl, accRi);
            aTr   = MF(xa[0][0][t], Brl, aTr);
            aTi   = MF(xa[1][0][t], Brl, aTi);

            accRr = MF(cRl, Brh, accRr);
            accRi = MF(cIl, Brh, accRi);
            aTr   = MF(xa[0][1][t], Brh, aTr);
            aTi   = MF(xa[1][1][t], Brh, aTi);

            accRr = MF(cIh, nBih, accRr);      // -Ci*Ti
            accRi = MF(cRh, sBih, accRi);      // ±Cr*Ti
            aTr   = MF(xa[1][0][t], nBih, aTr);// -Xi*Ti
            aTi   = MF(xa[0][0][t], Bih, aTi); // +Xr*Ti

            accRr = MF(cIh, nBil, accRr);
            accRi = MF(cRh, sBil, accRi);
            aTr   = MF(xa[1][0][t], nBil, aTr);
            aTi   = MF(xa[0][0][t], Bil, aTi);

            accRr = MF(cIl, nBih, accRr);
            accRi = MF(cRl, sBih, accRi);
            aTr   = MF(xa[1][1][t], nBih, aTr);
            aTi   = MF(xa[0][1][t], Bih, aTi);
        }

        __syncthreads();   // all waves done READING T_{k-1}

        // split aTr/aTi (cvt_pk) and write T_k in place (row-major T_k: LDS[r][c] = T_k[r][c])
        {
            const int c = 32 * qc + lrow;
            #pragma unroll
            for (int g = 0; g < 4; ++g) {
                int rbse = 32 * qr + 8 * g + 4 * lhi;
                HL r01 = split2(aTr[4 * g + 0], aTr[4 * g + 1]);
                HL r23 = split2(aTr[4 * g + 2], aTr[4 * g + 3]);
                HL i01 = split2(aTi[4 * g + 0], aTi[4 * g + 1]);
                HL i23 = split2(aTi[4 * g + 2], aTi[4 * g + 3]);
                uint2v hr, lr, hi2, li2;
                hr[0] = r01.h; lr[0] = r01.l; hr[1] = r23.h; lr[1] = r23.l;
                hi2[0] = i01.h; li2[0] = i01.l; hi2[1] = i23.h; li2[1] = i23.l;
                int off = (c * LSTRIDE + rbse) * 2;
                *(uint2v*)(smem + 0 * MATB + off) = hr;
                *(uint2v*)(smem + 1 * MATB + off) = lr;
                *(uint2v*)(smem + 2 * MATB + off) = hi2;
                *(uint2v*)(smem + 3 * MATB + off) = li2;
            }
        }
        __syncthreads();   // T_k visible
    }

    // ---- final coefficient term: C_7 (kslot 6) on T_7 ----
    {
        const char* cw = wsb + (size_t)6 * 32768;
        #pragma unroll
        for (int t = 0; t < 4; ++t) {
            short8v cRh = *(const short8v*)(cw + ((0 * 2 + qr) * 4 + t) * 1024 + lane * 16);
            short8v cRl = *(const short8v*)(cw + ((1 * 2 + qr) * 4 + t) * 1024 + lane * 16);
            short8v cIh = *(const short8v*)(cw + ((2 * 2 + qr) * 4 + t) * 1024 + lane * 16);
            short8v cIl = *(const short8v*)(cw + ((3 * 2 + qr) * 4 + t) * 1024 + lane * 16);
            short8v Brh = ldB(0, t), Brl = ldB(1, t);
            short8v Bih = ldB(2, t), Bil = ldB(3, t);
            short8v nBih = negf(Bih), nBil = negf(Bil);

            accRr = MF(cRh, Brh, accRr);
            accRi = MF(cIh, Brh, accRi);
            accRr = MF(cRh, Brl, accRr);
            accRi = MF(cIh, Brl, accRi);
            accRr = MF(cRl, Brh, accRr);
            accRi = MF(cIl, Brh, accRi);
            accRr = MF(cIh, nBih, accRr);
            accRi = MF(cRh, nBih, accRi);
            accRr = MF(cIh, nBil, accRr);
            accRi = MF(cRh, nBil, accRi);
            accRr = MF(cIl, nBih, accRr);
            accRi = MF(cRl, nBih, accRi);
        }
    }

    __syncthreads();   // done reading T region; reuse for f32 transpose
    {
        const int c = 32 * qc + lrow;
        #pragma unroll
        for (int g = 0; g < 4; ++g) {
            int rbse = 32 * qr + 8 * g + 4 * lhi;
            f32x4 vr, vi;
            #pragma unroll
            for (int j = 0; j < 4; ++j) { vr[j] = accRr[4 * g + j]; vi[j] = accRi[4 * g + j]; }
            *(f32x4*)(smem + (size_t)(0 * 4352 + c * LSTRIDE + rbse) * 4) = vr;
            *(f32x4*)(smem + (size_t)(1 * 4352 + c * LSTRIDE + rbse) * 4) = vi;
        }
    }
    __syncthreads();
    float* ob = out + b * 8192;
    #pragma unroll
    for (int s = 0; s < 8; ++s) {
        int f = s * 1024 + tid * 4;
        int p = f >> 12, m = (f >> 6) & 63, n = f & 63;
        *(f32x4*)(ob + f) = *(const f32x4*)(smem + (size_t)(p * 4352 + m * LSTRIDE + n) * 4);
    }
}

extern "C" void kernel_launch(void* const* d_in, const int* in_sizes, int n_in,
                              void* d_out, int out_size, void* d_ws, size_t ws_size,
                              hipStream_t stream) {
    const float* x    = (const float*)d_in[0];
    const float* coef = (const float*)d_in[1];
    float* out = (float*)d_out;
    char*  wsb = (char*)d_ws;
    const int B = in_sizes[0] / 8192;   // 2048

    pms_prep<<<64, 64, 0, stream>>>(coef, wsb);
    pms_main<<<B, 256, LDS_BYTES, stream>>>(x, wsb, out);
}

// Round 5
// 144.158 us; speedup vs baseline: 1.2978x; 1.0946x over previous
//
#include <hip/hip_runtime.h>

typedef __attribute__((ext_vector_type(4))) short short4v;
typedef __attribute__((ext_vector_type(8))) short short8v;
typedef __attribute__((ext_vector_type(2))) unsigned int uint2v;
typedef __attribute__((ext_vector_type(4))) unsigned int uint4v;
typedef __attribute__((ext_vector_type(4))) float f32x4;
typedef __attribute__((ext_vector_type(16))) float f32x16;

#define LSTRIDE 68                 // bf16 elems per LDS row (136 B; stride/8 odd -> conflict-free b64)
#define MATB (64 * LSTRIDE * 2)    // 8704 B per 64x64 bf16 matrix
#define REGA 0
#define REGB (4 * MATB)            // ping-pong region
#define LDS_BYTES (8 * MATB)       // 69632 -> 2 WG/CU

// ws: [kslot 0..6][mat 0..3][qr][t][lane*16B]; mat: 0=Cr_h 1=Cr_l 2=Ci_h 3=Ci_l
#define CFRAG_BYTES (7 * 4 * 2 * 4 * 1024)  // 229376
#define INIT_OFF CFRAG_BYTES                // + 32768: [part][qr][qc][lane][16 f32]

__device__ __forceinline__ short bf16h(float v) {
    union { float f; unsigned u; } x; x.f = v;
    unsigned r = x.u + 0x7FFFu + ((x.u >> 16) & 1u);
    return (short)(r >> 16);
}
__device__ __forceinline__ float bf16tof(short s) {
    union { unsigned u; float f; } x; x.u = ((unsigned)(unsigned short)s) << 16;
    return x.f;
}
// split two f32 into packed-bf16 high parts and packed-bf16 low (residual) parts
struct HL { unsigned h, l; };
__device__ __forceinline__ HL split2(float v0, float v1) {
    unsigned hp, lp;
    asm("v_cvt_pk_bf16_f32 %0, %1, %2" : "=v"(hp) : "v"(v0), "v"(v1));
    union { unsigned u; float f; } a, b;
    a.u = hp << 16;            // float of bf16(v0)
    b.u = hp & 0xffff0000u;    // float of bf16(v1)
    float l0 = v0 - a.f, l1 = v1 - b.f;
    asm("v_cvt_pk_bf16_f32 %0, %1, %2" : "=v"(lp) : "v"(l0), "v"(l1));
    HL r; r.h = hp; r.l = lp; return r;
}
__device__ __forceinline__ f32x16 MF(short8v a, short8v b, f32x16 c) {
    return __builtin_amdgcn_mfma_f32_32x32x16_bf16(a, b, c, 0, 0, 0);
}
__device__ __forceinline__ short8v negf(short8v a) {   // negate 8 bf16 (packed xor)
    uint4v u = __builtin_bit_cast(uint4v, a);
    u ^= 0x80008000u;
    return __builtin_bit_cast(short8v, u);
}

// ---------------- prep: coefficients -> ws ----------------
__global__ void pms_prep(const float* __restrict__ coef, char* __restrict__ wsb) {
    const int blk = blockIdx.x;
    const int lane = threadIdx.x;
    const int lrow = lane & 31, lhi = lane >> 5;
    if (blk < 56) {
        const int qr  = blk & 1;
        const int km  = blk >> 1;
        const int mat = km & 3;
        const int kk  = km >> 2;            // kslot 0..6 <-> coefficient index kk+1
        const int part = mat >> 1;
        const int lo   = mat & 1;
        const float* C = coef + (size_t)((kk + 1) * 2 + part) * 4096;
        for (int t = 0; t < 4; ++t) {
            short8v o;
            #pragma unroll
            for (int j = 0; j < 8; ++j) {
                int krow = 16 * t + 8 * lhi + j;
                int col  = 32 * qr + lrow;
                float v = C[krow * 64 + col];           // C^T[col][krow]
                short hh = bf16h(v);
                o[j] = lo ? bf16h(v - bf16tof(hh)) : hh;
            }
            *(short8v*)(wsb + ((size_t)blk * 4 + t) * 1024 + lane * 16) = o;
        }
    } else {
        const int id = blk - 56;            // [part][qr][qc]
        const int qc = id & 1, qr = (id >> 1) & 1, part = id >> 2;
        const float* C0 = coef + (size_t)part * 4096;
        float* dst = (float*)(wsb + INIT_OFF + (size_t)(((part * 2 + qr) * 2 + qc) * 64 + lane) * 64);
        #pragma unroll
        for (int v = 0; v < 16; ++v) {
            int r = 32 * qr + (v & 3) + 8 * (v >> 2) + 4 * lhi;  // D-layout row
            int c = 32 * qc + lrow;                               // D-layout col
            dst[v] = C0[c * 64 + r];        // C0^T[r][c]
        }
    }
}

// ---------------- main ----------------
__global__ __launch_bounds__(256, 2) void pms_main(
    const float* __restrict__ x, const char* __restrict__ wsb,
    float* __restrict__ out)
{
    extern __shared__ char smem[];
    const int tid  = threadIdx.x;
    const int lane = tid & 63;
    const int w    = tid >> 6;
    const int qr = w >> 1, qc = w & 1;
    const int lrow = lane & 31, lhi = lane >> 5;
    const size_t b = blockIdx.x;
    const float* xb = x + b * 8192;

    // ---- stage X (row-major) as split bf16 into REGA; doubles as T_1 ----
    #pragma unroll
    for (int s = 0; s < 8; ++s) {
        int f = s * 1024 + tid * 4;
        int p = f >> 12, m = (f >> 6) & 63, c = f & 63;
        f32x4 v = *(const f32x4*)(xb + f);
        HL a01 = split2(v[0], v[1]);
        HL a23 = split2(v[2], v[3]);
        uint2v h, l;
        h[0] = a01.h; l[0] = a01.l;
        h[1] = a23.h; l[1] = a23.l;
        int off = (m * LSTRIDE + c) * 2;
        *(uint2v*)(smem + REGA + (p * 2 + 0) * MATB + off) = h;
        *(uint2v*)(smem + REGA + (p * 2 + 1) * MATB + off) = l;
    }
    __syncthreads();

    // ---- one-time A-fragments of X^T (registers, all iterations) ----
    short8v xa[2][2][4];   // [r/i][h/l][ktile]
    #pragma unroll
    for (int pi = 0; pi < 2; ++pi)
    #pragma unroll
    for (int hl = 0; hl < 2; ++hl)
    #pragma unroll
    for (int t = 0; t < 4; ++t) {
        const short* mp = (const short*)(smem + REGA + (pi * 2 + hl) * MATB);
        short8v a;
        #pragma unroll
        for (int j = 0; j < 8; ++j)
            a[j] = mp[(16 * t + 8 * lhi + j) * LSTRIDE + 32 * qr + lrow];  // X^T[r][k]
        xa[pi][hl][t] = a;
    }

    // ---- accumulators init = C0^T fragments ----
    f32x16 accRr, accRi;
    {
        const f32x4* p0 = (const f32x4*)(wsb + INIT_OFF + (size_t)(((0 + qr) * 2 + qc) * 64 + lane) * 64);
        const f32x4* p1 = (const f32x4*)(wsb + INIT_OFF + (size_t)(((2 + qr) * 2 + qc) * 64 + lane) * 64);
        #pragma unroll
        for (int g = 0; g < 4; ++g) {
            f32x4 a = p0[g], c4 = p1[g];
            #pragma unroll
            for (int j = 0; j < 4; ++j) { accRr[4 * g + j] = a[j]; accRi[4 * g + j] = c4[j]; }
        }
    }

    // B-fragment: lane reads lds_T[n = 32qc+lrow][k = 16t+8lhi .. +7], two b64s
    auto ldB = [&](int rbase, int mat, int t) -> short8v {
        const short4v* p = (const short4v*)(smem + rbase + mat * MATB
                             + (32 * qc + lrow) * (LSTRIDE * 2) + 32 * t + 16 * lhi);
        short4v a = p[0], c4 = p[1];
        short8v r;
        #pragma unroll
        for (int j = 0; j < 4; ++j) { r[j] = a[j]; r[j + 4] = c4[j]; }
        return r;
    };

    int cur = REGA, nxt = REGB;

    // ---- fused loop: iteration k applies C_{k-1} to T_{k-1} AND computes T_k -> nxt ----
    for (int k = 2; k <= 7; ++k) {
        const char* cw = wsb + (size_t)(k - 2) * 32768;   // kslot k-2
        const bool k1 = (k == 2);

        // prefetch ALL 16 coefficient A-frags for this iteration (global, L2-resident)
        short8v cRh[4], cRl[4], cIh[4], cIl[4];
        #pragma unroll
        for (int t = 0; t < 4; ++t) {
            cRh[t] = *(const short8v*)(cw + ((0 * 2 + qr) * 4 + t) * 1024 + lane * 16);
            cRl[t] = *(const short8v*)(cw + ((1 * 2 + qr) * 4 + t) * 1024 + lane * 16);
            cIh[t] = *(const short8v*)(cw + ((2 * 2 + qr) * 4 + t) * 1024 + lane * 16);
            cIl[t] = *(const short8v*)(cw + ((3 * 2 + qr) * 4 + t) * 1024 + lane * 16);
        }
        // B prefetch t=0
        short8v Brh = ldB(cur, 0, 0), Brl = ldB(cur, 1, 0);
        short8v Bih = ldB(cur, 2, 0), Bil = ldB(cur, 3, 0);

        f32x16 aTr, aTi;
        #pragma unroll
        for (int v = 0; v < 16; ++v) { aTr[v] = 0.f; aTi[v] = 0.f; }

        #pragma unroll
        for (int t = 0; t < 4; ++t) {
            // issue next t's B-frag reads before this t's MFMA cluster
            short8v Nrh, Nrl, Nih, Nil;
            if (t < 3) {
                Nrh = ldB(cur, 0, t + 1); Nrl = ldB(cur, 1, t + 1);
                Nih = ldB(cur, 2, t + 1); Nil = ldB(cur, 3, t + 1);
            }
            short8v nBih = negf(Bih), nBil = negf(Bil);        // -Ti
            short8v sBih = k1 ? Bih : nBih;                    // sign quirk: +Cr*Ti at k=1 only
            short8v sBil = k1 ? Bil : nBil;

            __builtin_amdgcn_s_setprio(1);
            // 24 MFMAs, 4 independent chains round-robin
            accRr = MF(cRh[t], Brh, accRr);
            accRi = MF(cIh[t], Brh, accRi);
            aTr   = MF(xa[0][0][t], Brh, aTr);
            aTi   = MF(xa[1][0][t], Brh, aTi);

            accRr = MF(cRh[t], Brl, accRr);
            accRi = MF(cIh[t], Brl, accRi);
            aTr   = MF(xa[0][0][t], Brl, aTr);
            aTi   = MF(xa[1][0][t], Brl, aTi);

            accRr = MF(cRl[t], Brh, accRr);
            accRi = MF(cIl[t], Brh, accRi);
            aTr   = MF(xa[0][1][t], Brh, aTr);
            aTi   = MF(xa[1][1][t], Brh, aTi);

            accRr = MF(cIh[t], nBih, accRr);      // -Ci*Ti
            accRi = MF(cRh[t], sBih, accRi);      // ±Cr*Ti
            aTr   = MF(xa[1][0][t], nBih, aTr);   // -Xi*Ti
            aTi   = MF(xa[0][0][t], Bih, aTi);    // +Xr*Ti

            accRr = MF(cIh[t], nBil, accRr);
            accRi = MF(cRh[t], sBil, accRi);
            aTr   = MF(xa[1][0][t], nBil, aTr);
            aTi   = MF(xa[0][0][t], Bil, aTi);

            accRr = MF(cIl[t], nBih, accRr);
            accRi = MF(cRl[t], sBih, accRi);
            aTr   = MF(xa[1][1][t], nBih, aTr);
            aTi   = MF(xa[0][1][t], Bih, aTi);
            __builtin_amdgcn_s_setprio(0);

            if (t < 3) { Brh = Nrh; Brl = Nrl; Bih = Nih; Bil = Nil; }
        }

        // split aTr/aTi (cvt_pk) and write T_k into nxt (no barrier needed before: nxt != cur)
        {
            const int c = 32 * qc + lrow;
            #pragma unroll
            for (int g = 0; g < 4; ++g) {
                int rbse = 32 * qr + 8 * g + 4 * lhi;
                HL r01 = split2(aTr[4 * g + 0], aTr[4 * g + 1]);
                HL r23 = split2(aTr[4 * g + 2], aTr[4 * g + 3]);
                HL i01 = split2(aTi[4 * g + 0], aTi[4 * g + 1]);
                HL i23 = split2(aTi[4 * g + 2], aTi[4 * g + 3]);
                uint2v hr, lr, hi2, li2;
                hr[0] = r01.h; lr[0] = r01.l; hr[1] = r23.h; lr[1] = r23.l;
                hi2[0] = i01.h; li2[0] = i01.l; hi2[1] = i23.h; li2[1] = i23.l;
                int off = (c * LSTRIDE + rbse) * 2;
                *(uint2v*)(smem + nxt + 0 * MATB + off) = hr;
                *(uint2v*)(smem + nxt + 1 * MATB + off) = lr;
                *(uint2v*)(smem + nxt + 2 * MATB + off) = hi2;
                *(uint2v*)(smem + nxt + 3 * MATB + off) = li2;
            }
        }
        __syncthreads();   // T_k visible; also guarantees everyone done reading cur
        int tmp = cur; cur = nxt; nxt = tmp;
    }

    // ---- final coefficient term: C_7 (kslot 6) on T_7 (in cur) ----
    {
        const char* cw = wsb + (size_t)6 * 32768;
        short8v cRh[4], cRl[4], cIh[4], cIl[4];
        #pragma unroll
        for (int t = 0; t < 4; ++t) {
            cRh[t] = *(const short8v*)(cw + ((0 * 2 + qr) * 4 + t) * 1024 + lane * 16);
            cRl[t] = *(const short8v*)(cw + ((1 * 2 + qr) * 4 + t) * 1024 + lane * 16);
            cIh[t] = *(const short8v*)(cw + ((2 * 2 + qr) * 4 + t) * 1024 + lane * 16);
            cIl[t] = *(const short8v*)(cw + ((3 * 2 + qr) * 4 + t) * 1024 + lane * 16);
        }
        short8v Brh = ldB(cur, 0, 0), Brl = ldB(cur, 1, 0);
        short8v Bih = ldB(cur, 2, 0), Bil = ldB(cur, 3, 0);
        #pragma unroll
        for (int t = 0; t < 4; ++t) {
            short8v Nrh, Nrl, Nih, Nil;
            if (t < 3) {
                Nrh = ldB(cur, 0, t + 1); Nrl = ldB(cur, 1, t + 1);
                Nih = ldB(cur, 2, t + 1); Nil = ldB(cur, 3, t + 1);
            }
            short8v nBih = negf(Bih), nBil = negf(Bil);

            __builtin_amdgcn_s_setprio(1);
            accRr = MF(cRh[t], Brh, accRr);
            accRi = MF(cIh[t], Brh, accRi);
            accRr = MF(cRh[t], Brl, accRr);
            accRi = MF(cIh[t], Brl, accRi);
            accRr = MF(cRl[t], Brh, accRr);
            accRi = MF(cIl[t], Brh, accRi);
            accRr = MF(cIh[t], nBih, accRr);
            accRi = MF(cRh[t], nBih, accRi);
            accRr = MF(cIh[t], nBil, accRr);
            accRi = MF(cRh[t], nBil, accRi);
            accRr = MF(cIl[t], nBih, accRr);
            accRi = MF(cRl[t], nBih, accRi);
            __builtin_amdgcn_s_setprio(0);

            if (t < 3) { Brh = Nrh; Brl = Nrl; Bih = Nih; Bil = Nil; }
        }
    }

    __syncthreads();   // done reading cur; nxt region is dead -> f32 transpose staging
    {
        const int c = 32 * qc + lrow;
        #pragma unroll
        for (int g = 0; g < 4; ++g) {
            int rbse = 32 * qr + 8 * g + 4 * lhi;
            f32x4 vr, vi;
            #pragma unroll
            for (int j = 0; j < 4; ++j) { vr[j] = accRr[4 * g + j]; vi[j] = accRi[4 * g + j]; }
            *(f32x4*)(smem + nxt + (size_t)(0 * 4352 + c * LSTRIDE + rbse) * 4) = vr;
            *(f32x4*)(smem + nxt + (size_t)(1 * 4352 + c * LSTRIDE + rbse) * 4) = vi;
        }
    }
    __syncthreads();
    float* ob = out + b * 8192;
    #pragma unroll
    for (int s = 0; s < 8; ++s) {
        int f = s * 1024 + tid * 4;
        int p = f >> 12, m = (f >> 6) & 63, n = f & 63;
        *(f32x4*)(ob + f) = *(const f32x4*)(smem + nxt + (size_t)(p * 4352 + m * LSTRIDE + n) * 4);
    }
}

extern "C" void kernel_launch(void* const* d_in, const int* in_sizes, int n_in,
                              void* d_out, int out_size, void* d_ws, size_t ws_size,
                              hipStream_t stream) {
    const float* x    = (const float*)d_in[0];
    const float* coef = (const float*)d_in[1];
    float* out = (float*)d_out;
    char*  wsb = (char*)d_ws;
    const int B = in_sizes[0] / 8192;   // 2048

    (void)hipFuncSetAttribute(reinterpret_cast<const void*>(&pms_main),
                              hipFuncAttributeMaxDynamicSharedMemorySize, LDS_BYTES);

    pms_prep<<<64, 64, 0, stream>>>(coef, wsb);
    pms_main<<<B, 256, LDS_BYTES, stream>>>(x, wsb, out);
}